// Round 10
// baseline (145.912 us; speedup 1.0000x reference)
//
#include <hip/hip_runtime.h>
#include <hip/hip_bf16.h>
#include <stdint.h>

#define B_  8
#define T_  2048
#define E_  512

typedef __attribute__((ext_vector_type(8))) __bf16 bf16x8;
typedef __attribute__((ext_vector_type(8))) unsigned short ushort8;
typedef __attribute__((ext_vector_type(4))) unsigned short ushort4v;
typedef __attribute__((ext_vector_type(4))) float f32x4;

__device__ __forceinline__ float bf2f(unsigned short u) {
  union { unsigned int u; float f; } c; c.u = ((unsigned int)u) << 16; return c.f;
}
__device__ __forceinline__ unsigned short f2bf(float f) {
  union { float f; unsigned int u; } c; c.f = f;
  unsigned int u = c.u;
  unsigned int r = (u + 0x7FFFu + ((u >> 16) & 1u)) >> 16;
  return (unsigned short)r;
}

__device__ __forceinline__ void gload_lds16(const void* g, void* l) {
  __builtin_amdgcn_global_load_lds(
      (const __attribute__((address_space(1))) uint32_t*)g,
      (__attribute__((address_space(3))) uint32_t*)l, 16, 0, 0);
}

// ---------------- fused bf16-convert + transpose ----------------
__global__ __launch_bounds__(256)
void trans_conv_kernel(const float* __restrict__ x, unsigned short* __restrict__ xbf,
                       unsigned short* __restrict__ xT) {
  __shared__ unsigned short tile[64][66];
  const int t0 = blockIdx.x * 64, e0 = blockIdx.y * 64, b = blockIdx.z;
  const int tid = threadIdx.x;
  const float* xb = x + ((size_t)b * T_ + t0) * E_ + e0;
  unsigned short* xbf_b = xbf + ((size_t)b * T_ + t0) * E_ + e0;
#pragma unroll
  for (int it = 0; it < 4; ++it) {
    int tr = (tid >> 4) + it * 16;
    int ec = (tid & 15) * 4;
    float4 f = *reinterpret_cast<const float4*>(xb + (size_t)tr * E_ + ec);
    ushort4v o;
    o[0] = f2bf(f.x); o[1] = f2bf(f.y); o[2] = f2bf(f.z); o[3] = f2bf(f.w);
    *reinterpret_cast<ushort4v*>(xbf_b + (size_t)tr * E_ + ec) = o;
    tile[ec + 0][tr] = o[0];
    tile[ec + 1][tr] = o[1];
    tile[ec + 2][tr] = o[2];
    tile[ec + 3][tr] = o[3];
  }
  __syncthreads();
  unsigned short* dst = xT + ((size_t)b * E_ + e0) * T_ + t0;
#pragma unroll
  for (int it = 0; it < 2; ++it) {
    int er = (tid >> 3) + it * 32;
    int tg = (tid & 7) * 8;
    ushort8 r;
#pragma unroll
    for (int j = 0; j < 8; ++j) r[j] = tile[er][tg + j];
    *reinterpret_cast<ushort8*>(dst + (size_t)er * T_ + tg) = r;
  }
}

// WT[n][kk] = (n<512 ? Wq[kk][n]*scale : Wk[kk][n-512]);  bqk[n] fused bias
__global__ __launch_bounds__(256)
void conv_w_kernel(const float* __restrict__ Wq, const float* __restrict__ Wk,
                   const float* __restrict__ bq, const float* __restrict__ bk,
                   unsigned short* __restrict__ WT, float* __restrict__ bqk, float scale) {
  int idx = blockIdx.x * 256 + threadIdx.x;
  int n  = idx >> 9;
  int kk = idx & 511;
  float v = (n < E_) ? Wq[kk * E_ + n] * scale : Wk[kk * E_ + (n - E_)];
  WT[idx] = f2bf(v);
  if (idx < 2 * E_) {
    float bv = (idx < E_) ? bq[idx] * scale : bk[idx - E_];
    bqk[idx] = bv;
  }
}

// ====== 256x128 8-wave 4-phase GEMM, counted vmcnt, SPILL-PROOF ======
// BK=64, 512 thr (4M x 2N waves), per-wave 64x64 -> acc=64 regs (~145 total,
// far under the 256 unified budget; r7/r9's 512-thr acc=128 version sat at the
// edge and spilled -> spill ops corrupt vmcnt counts; this cannot).
// LDS per buf (shorts): A rows 0-255 @[0,16384), B rows 0-127 @[16384,24576).
// Buf stride 24576 shorts; 2 bufs = 96 KiB.
// Q order (mh,nh): ph0=(0,0) ph1=(0,1) ph2=(1,0) ph3=(1,1).
// B ds_reads all complete by ph1 -> B-region of live buf dead at ph2.
// Slots: A0(t+1)@ph0->pn, A1(t+1)@ph1->pn, B(t+2)@ph2->p(live, dead region).
// Tile-end wait vmcnt(2): retires tile t+1's 6 loads, B(t+2)x2 stays in flight.
#define STG2(gbase, ld, hoff, pbuf, kt) do {                                    \
  gload_lds16((gbase) + (long long)(kt) * 64,                                   \
              &sm[(pbuf) * 24576 + (hoff) + wv * 512]);                         \
  gload_lds16((gbase) + (long long)64 * (ld) + (long long)(kt) * 64,            \
              &sm[(pbuf) * 24576 + (hoff) + 4096 + wv * 512]);                  \
} while (0)

#define RD_A4(pp, mh) do {                                                      \
  const int ab = (pp) * 24576 + (wr * 64 + (mh) * 32 + fr) * 64;                \
  _Pragma("unroll") for (int m_ = 0; m_ < 2; ++m_) {                            \
    aA[m_][0] = *reinterpret_cast<const bf16x8*>(&sm[ab + m_ * 1024 + c0]);     \
    aA[m_][1] = *reinterpret_cast<const bf16x8*>(&sm[ab + m_ * 1024 + c1]);     \
  } } while (0)

#define RD_B4(pp, nh) do {                                                      \
  const int bb = (pp) * 24576 + 16384 + (wc * 64 + (nh) * 32 + fr) * 64;        \
  _Pragma("unroll") for (int n_ = 0; n_ < 2; ++n_) {                            \
    bB[nh][n_][0] = *reinterpret_cast<const bf16x8*>(&sm[bb + n_ * 1024 + c0]); \
    bB[nh][n_][1] = *reinterpret_cast<const bf16x8*>(&sm[bb + n_ * 1024 + c1]); \
  } } while (0)

#define MFMA_Q4(mh, nh) do {                                                    \
  _Pragma("unroll") for (int m_ = 0; m_ < 2; ++m_)                              \
  _Pragma("unroll") for (int n_ = 0; n_ < 2; ++n_) {                            \
    acc[(mh)*2+m_][(nh)*2+n_] = __builtin_amdgcn_mfma_f32_16x16x32_bf16(        \
        aA[m_][0], bB[nh][n_][0], acc[(mh)*2+m_][(nh)*2+n_], 0, 0, 0);          \
    acc[(mh)*2+m_][(nh)*2+n_] = __builtin_amdgcn_mfma_f32_16x16x32_bf16(        \
        aA[m_][1], bB[nh][n_][1], acc[(mh)*2+m_][(nh)*2+n_], 0, 0, 0);          \
  } } while (0)

template<int DO_EXP>
__global__ __launch_bounds__(512)
void gemm4p(const unsigned short* __restrict__ A, int lda, long long strA,
            const unsigned short* __restrict__ B, int ldb, long long strB,
            unsigned short* __restrict__ Cg, int ldc, long long strC,
            int K, const float* __restrict__ bias, int NBX, int NBY,
            float* __restrict__ Rg)
{
  __shared__ unsigned short sm[49152];   // 96 KiB
  const int tid  = threadIdx.x;
  const int lane = tid & 63;
  const int wv   = tid >> 6;
  const int wr   = wv >> 1;          // 0..3 (M)
  const int wc   = wv & 1;           // 0..1 (N)
  const int fr   = lane & 15;

  const int nwg = gridDim.x, bid = blockIdx.x;
  const int qq = nwg >> 3, rr = nwg & 7, xc = bid & 7, ii = bid >> 3;
  const int wg = (xc < rr ? xc * (qq + 1) : rr * (qq + 1) + (xc - rr) * qq) + ii;
  const int bx = wg % NBX;
  const int tt = wg / NBX;
  const int by = tt % NBY;
  const int bz = tt / NBY;

  const long long m0 = (long long)by * 256;
  const long long n0 = (long long)bx * 128;
  const unsigned short* Ab = A + (long long)bz * strA + m0 * lda;
  const unsigned short* Bb = B + (long long)bz * strB + n0 * ldb;

  const int srow = tid >> 3;                                   // 0..63
  const int scol = ((tid & 7) * 8) ^ ((srow & 7) << 3);
  const unsigned short* gA0 = Ab + (long long)srow * lda + scol;
  const unsigned short* gA1 = Ab + (long long)(128 + srow) * lda + scol;
  const unsigned short* gB  = Bb + (long long)srow * ldb + scol;

  const int xorc = (fr & 7) << 3;
  const int q8   = (lane >> 4) * 8;
  const int c0   = q8 ^ xorc;
  const int c1   = (32 + q8) ^ xorc;

  f32x4 acc[4][4];
#pragma unroll
  for (int i = 0; i < 4; ++i)
#pragma unroll
    for (int j = 0; j < 4; ++j) acc[i][j] = (f32x4){0.f, 0.f, 0.f, 0.f};

  bf16x8 aA[2][2], bB[2][2][2];
  const int NT = K >> 6;   // >= 2 in all uses

  // prologue: tile0 (A0,A1,B) -> buf0; B(1) -> buf1.  8 issued, vmcnt(2)
  // retires the oldest 6 = tile 0; B(1)x2 stays in flight.
  STG2(gA0, lda, 0,     0, 0);
  STG2(gA1, lda, 8192,  0, 0);
  STG2(gB,  ldb, 16384, 0, 0);
  STG2(gB,  ldb, 16384, 1, 1);
  asm volatile("s_waitcnt vmcnt(2)" ::: "memory");
  __builtin_amdgcn_s_barrier();

  int p = 0;
  for (int t = 0; t < NT; ++t) {
    const int pn = p ^ 1;
    // ---- ph0: Q(0,0); stage A0(t+1) -> pn ----
    RD_A4(p, 0);
    RD_B4(p, 0);
    if (t + 1 < NT) STG2(gA0, lda, 0, pn, t + 1);
    __builtin_amdgcn_s_barrier();
    __builtin_amdgcn_s_setprio(1); MFMA_Q4(0, 0); __builtin_amdgcn_s_setprio(0);
    __builtin_amdgcn_s_barrier();
    // ---- ph1: Q(0,1); stage A1(t+1) -> pn ----
    RD_B4(p, 1);
    if (t + 1 < NT) STG2(gA1, lda, 8192, pn, t + 1);
    __builtin_amdgcn_s_barrier();
    __builtin_amdgcn_s_setprio(1); MFMA_Q4(0, 1); __builtin_amdgcn_s_setprio(0);
    __builtin_amdgcn_s_barrier();
    // ---- ph2: Q(1,0); stage B(t+2) -> p (B-region dead since ph1 barrier) ----
    RD_A4(p, 1);
    if (t + 2 < NT) STG2(gB, ldb, 16384, p, t + 2);
    __builtin_amdgcn_s_barrier();
    __builtin_amdgcn_s_setprio(1); MFMA_Q4(1, 0); __builtin_amdgcn_s_setprio(0);
    __builtin_amdgcn_s_barrier();
    // ---- ph3: Q(1,1); counted wait ----
    __builtin_amdgcn_s_setprio(1); MFMA_Q4(1, 1); __builtin_amdgcn_s_setprio(0);
    if (t + 2 < NT) asm volatile("s_waitcnt vmcnt(2)" ::: "memory");
    else            asm volatile("s_waitcnt vmcnt(0)" ::: "memory");
    __builtin_amdgcn_s_barrier();
    p = pn;
  }

  // ---- epilogue ----
  const int rq = (lane >> 4) * 4;
  if (DO_EXP) {
#pragma unroll
    for (int m = 0; m < 4; ++m)
#pragma unroll
      for (int n = 0; n < 4; ++n)
#pragma unroll
        for (int j = 0; j < 4; ++j) acc[m][n][j] = __expf(acc[m][n][j]);
  } else if (bias) {
#pragma unroll
    for (int n = 0; n < 4; ++n) {
      const float bv = bias[n0 + wc * 64 + n * 16 + fr];
#pragma unroll
      for (int m = 0; m < 4; ++m)
#pragma unroll
        for (int j = 0; j < 4; ++j) acc[m][n][j] += bv;
    }
  }
  float* rps = (float*)sm;               // bytes [0, 2048): [2 wc][256 rows]
  unsigned short* cs = sm + 4096;        // bytes [8192, 77824): 256 x 136
  if (DO_EXP) {
#pragma unroll
    for (int m = 0; m < 4; ++m)
#pragma unroll
      for (int j = 0; j < 4; ++j) {
        float s = acc[m][0][j] + acc[m][1][j] + acc[m][2][j] + acc[m][3][j];
        s += __shfl_xor(s, 1); s += __shfl_xor(s, 2);
        s += __shfl_xor(s, 4); s += __shfl_xor(s, 8);
        const int lrow = wr * 64 + m * 16 + rq + j;
        if (fr == 0) rps[wc * 256 + lrow] = s;
      }
  }
#pragma unroll
  for (int m = 0; m < 4; ++m)
#pragma unroll
    for (int j = 0; j < 4; ++j) {
      const int lrow = wr * 64 + m * 16 + rq + j;
#pragma unroll
      for (int n = 0; n < 4; ++n)
        cs[lrow * 136 + wc * 64 + n * 16 + fr] = f2bf(acc[m][n][j]);
    }
  __syncthreads();
  if (DO_EXP && tid < 256) {
    const float s = rps[tid] + rps[256 + tid];
    Rg[((long long)bz * NBX + bx) * 2048 + m0 + tid] = s;
  }
  unsigned short* C = Cg + (long long)bz * strC;
#pragma unroll
  for (int it = 0; it < 8; ++it) {
    const int row = it * 32 + (tid >> 4);
    const int ch = tid & 15;
    ushort8 v = *reinterpret_cast<const ushort8*>(&cs[row * 136 + ch * 8]);
    *reinterpret_cast<ushort8*>(&C[(m0 + row) * ldc + n0 + ch * 8]) = v;
  }
}

// ---------------- invR[b][t] = 1 / sum_c R[b][c][t]  (fixed order) ----------------
__global__ __launch_bounds__(256)
void rowsum_inv_kernel(const float* __restrict__ R, float* __restrict__ invR) {
  const int i = blockIdx.x * 256 + threadIdx.x;   // 0..16383
  const int b = i >> 11, t = i & 2047;
  float s = 0.f;
#pragma unroll
  for (int c = 0; c < 16; ++c) s += R[((long long)(b * 16 + c)) * 2048 + t];
  invR[i] = 1.0f / s;
}

// ====== 128x128 PV GEMM — round-8 PASSING kernel, verbatim (OUT = f32 * invR) ======
#define STAGE_A(pbuf, kt) do {                                                  \
  _Pragma("unroll") for (int r_ = 0; r_ < 4; ++r_)                              \
    gload_lds16(gA + (long long)(r_ * 32) * lda + (long long)(kt) * 64,         \
                &sm[(pbuf) * 16384 + r_ * 2048 + tid * 8]);                     \
} while (0)

#define STAGE_B(pbuf, kt) do {                                                  \
  _Pragma("unroll") for (int r_ = 0; r_ < 4; ++r_)                              \
    gload_lds16(gB + (long long)(r_ * 32) * ldb + (long long)(kt) * 64,         \
                &sm[(pbuf) * 16384 + 8192 + r_ * 2048 + tid * 8]);              \
} while (0)

__global__ __launch_bounds__(256)
void gemm_pv(const unsigned short* __restrict__ A, int lda, long long strA,
             const unsigned short* __restrict__ B, int ldb, long long strB,
             const float* __restrict__ invR,
             float* __restrict__ C, int ldc, long long strC, int K)
{
  __shared__ unsigned short sm[32768];   // 64 KiB
  const int tid  = threadIdx.x;
  const int lane = tid & 63;
  const int wv   = tid >> 6;
  const int wrp  = wv >> 1;
  const int wcp  = wv & 1;
  const int fr   = lane & 15;

  const int nwg = gridDim.x, bid = blockIdx.x;
  const int qq = nwg >> 3, rr = nwg & 7, xc = bid & 7, ii = bid >> 3;
  const int wg = (xc < rr ? xc * (qq + 1) : rr * (qq + 1) + (xc - rr) * qq) + ii;
  const int bx = wg & 3;
  const int by = (wg >> 2) & 15;
  const int bz = wg >> 6;

  const long long m0 = (long long)by * 128;
  const long long n0 = (long long)bx * 128;
  const unsigned short* Ab = A + (long long)bz * strA + m0 * lda;
  const unsigned short* Bb = B + (long long)bz * strB + n0 * ldb;

  const int srow = tid >> 3;
  const int scol = ((tid & 7) * 8) ^ ((srow & 7) << 3);
  const unsigned short* gA = Ab + (long long)srow * lda + scol;
  const unsigned short* gB = Bb + (long long)srow * ldb + scol;

  const int xorc  = (fr & 7) << 3;
  const int q8    = (lane >> 4) * 8;
  const int c0    = q8 ^ xorc;
  const int c1    = (32 + q8) ^ xorc;
  const int aRow  = (wrp * 64 + fr) * 64;
  const int bRow  = 8192 + (wcp * 64 + fr) * 64;

  f32x4 acc[4][4];
#pragma unroll
  for (int i = 0; i < 4; ++i)
#pragma unroll
    for (int j = 0; j < 4; ++j) acc[i][j] = (f32x4){0.f, 0.f, 0.f, 0.f};

  bf16x8 aA[4][2], bB2[2][2];
  const int NT = K >> 6;

  STAGE_A(0, 0);
  STAGE_B(0, 0);
  STAGE_A(1, 1);
  asm volatile("s_waitcnt vmcnt(4)" ::: "memory");
  __builtin_amdgcn_s_barrier();

  int p = 0;
  for (int t = 0; t < NT; ++t) {
    const int pb = p * 16384;
    const int pn = p ^ 1;
    if (t + 1 < NT) STAGE_B(pn, t + 1);
#pragma unroll
    for (int m = 0; m < 4; ++m) {
      aA[m][0] = *reinterpret_cast<const bf16x8*>(&sm[pb + aRow + m * 1024 + c0]);
      aA[m][1] = *reinterpret_cast<const bf16x8*>(&sm[pb + aRow + m * 1024 + c1]);
    }
#pragma unroll
    for (int n = 0; n < 2; ++n) {
      bB2[n][0] = *reinterpret_cast<const bf16x8*>(&sm[pb + bRow + n * 1024 + c0]);
      bB2[n][1] = *reinterpret_cast<const bf16x8*>(&sm[pb + bRow + n * 1024 + c1]);
    }
    __builtin_amdgcn_s_setprio(1);
#pragma unroll
    for (int m = 0; m < 4; ++m)
#pragma unroll
      for (int n = 0; n < 2; ++n) {
        acc[m][n] = __builtin_amdgcn_mfma_f32_16x16x32_bf16(aA[m][0], bB2[n][0], acc[m][n], 0, 0, 0);
        acc[m][n] = __builtin_amdgcn_mfma_f32_16x16x32_bf16(aA[m][1], bB2[n][1], acc[m][n], 0, 0, 0);
      }
    __builtin_amdgcn_s_setprio(0);
    __builtin_amdgcn_s_barrier();
    if (t + 2 < NT) STAGE_A(p, t + 2);
#pragma unroll
    for (int n = 0; n < 2; ++n) {
      bB2[n][0] = *reinterpret_cast<const bf16x8*>(&sm[pb + bRow + (2 + n) * 1024 + c0]);
      bB2[n][1] = *reinterpret_cast<const bf16x8*>(&sm[pb + bRow + (2 + n) * 1024 + c1]);
    }
    __builtin_amdgcn_s_setprio(1);
#pragma unroll
    for (int m = 0; m < 4; ++m)
#pragma unroll
      for (int n = 0; n < 2; ++n) {
        acc[m][2 + n] = __builtin_amdgcn_mfma_f32_16x16x32_bf16(aA[m][0], bB2[n][0], acc[m][2 + n], 0, 0, 0);
        acc[m][2 + n] = __builtin_amdgcn_mfma_f32_16x16x32_bf16(aA[m][1], bB2[n][1], acc[m][2 + n], 0, 0, 0);
      }
    __builtin_amdgcn_s_setprio(0);
    if (t + 2 < NT) asm volatile("s_waitcnt vmcnt(4)" ::: "memory");
    else            asm volatile("s_waitcnt vmcnt(0)" ::: "memory");
    __builtin_amdgcn_s_barrier();
    p = pn;
  }

  const int rq = (lane >> 4) * 4;
  float* Cb = C + (long long)bz * strC;
#pragma unroll
  for (int m = 0; m < 4; ++m)
#pragma unroll
    for (int j = 0; j < 4; ++j) {
      const int lrow = wrp * 64 + m * 16 + rq + j;
      const long long row = m0 + lrow;
      const float inv = invR[bz * 2048 + row];
#pragma unroll
      for (int n = 0; n < 4; ++n)
        Cb[row * ldc + n0 + wcp * 64 + n * 16 + fr] = acc[m][n][j] * inv;
    }
}

// ---------------- launch ----------------
extern "C" void kernel_launch(void* const* d_in, const int* in_sizes, int n_in,
                              void* d_out, int out_size, void* d_ws, size_t ws_size,
                              hipStream_t stream)
{
  const float* x  = (const float*)d_in[0];
  const float* Wq = (const float*)d_in[1];
  const float* bq = (const float*)d_in[2];
  const float* Wk = (const float*)d_in[3];
  const float* bk = (const float*)d_in[4];
  float* out = (float*)d_out;

  char* w = (char*)d_ws;
  unsigned short* xbf  = (unsigned short*)w;  w += (size_t)B_ * T_ * E_ * 2;
  unsigned short* xT   = (unsigned short*)w;  w += (size_t)B_ * T_ * E_ * 2;
  unsigned short* WT   = (unsigned short*)w;  w += (size_t)2 * E_ * E_ * 2;
  float*          bqk  = (float*)w;           w += (size_t)2 * E_ * 4;
  float*          R    = (float*)w;           w += (size_t)B_ * 16 * T_ * 4;     // 2 MB
  float*          invR = (float*)w;           w += (size_t)B_ * T_ * 4;          // 64 KB
  unsigned short* qk   = (unsigned short*)w;  w += (size_t)B_ * T_ * 2 * E_ * 2;
  unsigned short* attn = (unsigned short*)w;  w += (size_t)B_ * T_ * T_ * 2;

  const float scale = 0.044194173824159216f;  // 512^-0.5

  trans_conv_kernel<<<dim3(32, 8, 8), 256, 0, stream>>>(x, xbf, xT);
  conv_w_kernel<<<2048, 256, 0, stream>>>(Wq, Wk, bq, bk, WT, bqk, scale);

  // qk[16384, 1024] = xbf @ WT^T (+bias)   grid 8x64 = 512 blocks
  gemm4p<0><<<512, 512, 0, stream>>>(
      xbf, E_, 0, WT, E_, 0, qk, 2 * E_, 0, E_, bqk, 8, 64, nullptr);

  // P[b][2048,2048] = exp(q_b @ k_b^T) + partial rowsums   grid 16x8x8 = 1024
  gemm4p<1><<<1024, 512, 0, stream>>>(
      qk, 2 * E_, (long long)T_ * 2 * E_,
      qk + E_, 2 * E_, (long long)T_ * 2 * E_,
      attn, T_, (long long)T_ * T_, E_, nullptr, 16, 8, R);

  rowsum_inv_kernel<<<64, 256, 0, stream>>>(R, invR);

  // out[b][2048,512] = (P_b @ x_b) * invR   grid 4x16x8 = 512
  gemm_pv<<<512, 256, 0, stream>>>(
      attn, T_, (long long)T_ * T_,
      xT, T_, (long long)E_ * T_,
      invR, out, E_, (long long)T_ * E_, T_);
}

// Round 11
// 143.051 us; speedup vs baseline: 1.0200x; 1.0200x over previous
//
#include <hip/hip_runtime.h>
#include <hip/hip_bf16.h>
#include <stdint.h>

#define B_  8
#define T_  2048
#define E_  512

typedef __attribute__((ext_vector_type(8))) __bf16 bf16x8;
typedef __attribute__((ext_vector_type(8))) unsigned short ushort8;
typedef __attribute__((ext_vector_type(4))) unsigned short ushort4v;
typedef __attribute__((ext_vector_type(4))) float f32x4;

__device__ __forceinline__ float bf2f(unsigned short u) {
  union { unsigned int u; float f; } c; c.u = ((unsigned int)u) << 16; return c.f;
}
__device__ __forceinline__ unsigned short f2bf(float f) {
  union { float f; unsigned int u; } c; c.f = f;
  unsigned int u = c.u;
  unsigned int r = (u + 0x7FFFu + ((u >> 16) & 1u)) >> 16;
  return (unsigned short)r;
}

__device__ __forceinline__ void gload_lds16(const void* g, void* l) {
  __builtin_amdgcn_global_load_lds(
      (const __attribute__((address_space(1))) uint32_t*)g,
      (__attribute__((address_space(3))) uint32_t*)l, 16, 0, 0);
}

// ---------------- fused bf16-convert + transpose ----------------
__global__ __launch_bounds__(256)
void trans_conv_kernel(const float* __restrict__ x, unsigned short* __restrict__ xbf,
                       unsigned short* __restrict__ xT) {
  __shared__ unsigned short tile[64][66];
  const int t0 = blockIdx.x * 64, e0 = blockIdx.y * 64, b = blockIdx.z;
  const int tid = threadIdx.x;
  const float* xb = x + ((size_t)b * T_ + t0) * E_ + e0;
  unsigned short* xbf_b = xbf + ((size_t)b * T_ + t0) * E_ + e0;
#pragma unroll
  for (int it = 0; it < 4; ++it) {
    int tr = (tid >> 4) + it * 16;
    int ec = (tid & 15) * 4;
    float4 f = *reinterpret_cast<const float4*>(xb + (size_t)tr * E_ + ec);
    ushort4v o;
    o[0] = f2bf(f.x); o[1] = f2bf(f.y); o[2] = f2bf(f.z); o[3] = f2bf(f.w);
    *reinterpret_cast<ushort4v*>(xbf_b + (size_t)tr * E_ + ec) = o;
    tile[ec + 0][tr] = o[0];
    tile[ec + 1][tr] = o[1];
    tile[ec + 2][tr] = o[2];
    tile[ec + 3][tr] = o[3];
  }
  __syncthreads();
  unsigned short* dst = xT + ((size_t)b * E_ + e0) * T_ + t0;
#pragma unroll
  for (int it = 0; it < 2; ++it) {
    int er = (tid >> 3) + it * 32;
    int tg = (tid & 7) * 8;
    ushort8 r;
#pragma unroll
    for (int j = 0; j < 8; ++j) r[j] = tile[er][tg + j];
    *reinterpret_cast<ushort8*>(dst + (size_t)er * T_ + tg) = r;
  }
}

// WT[n][kk] = (n<512 ? Wq[kk][n]*scale : Wk[kk][n-512]);  bqk[n] fused bias
__global__ __launch_bounds__(256)
void conv_w_kernel(const float* __restrict__ Wq, const float* __restrict__ Wk,
                   const float* __restrict__ bq, const float* __restrict__ bk,
                   unsigned short* __restrict__ WT, float* __restrict__ bqk, float scale) {
  int idx = blockIdx.x * 256 + threadIdx.x;
  int n  = idx >> 9;
  int kk = idx & 511;
  float v = (n < E_) ? Wq[kk * E_ + n] * scale : Wk[kk * E_ + (n - E_)];
  WT[idx] = f2bf(v);
  if (idx < 2 * E_) {
    float bv = (idx < E_) ? bq[idx] * scale : bk[idx - E_];
    bqk[idx] = bv;
  }
}

// ====== 256x128 GEMM, 8 waves (4M x 2N), counted-vmcnt 2-barrier schedule ======
// Per-wave 64x64 (acc=64 regs, spill-safe). BK=64, LDS 96 KiB (2 bufs x 48KB).
// Exact gemm128c schedule (passed r8/r10): stage B(t+1)->pn @ph0; stage
// A(t+2)->p-live A-region @ph1 (A fully consumed @ph0, barrier-covered).
// Tile-end wait vmcnt(4): outstanding = A(t+1)4 + B(t+1)2 + A(t+2)4 = 10,
// retires 6 = all of tile t+1, keeps A(t+2) in flight across the barrier.
// OUT: 0 = bf16 +bias; 1 = bf16 exp + partial rowsum R.
#define STAGE_A6(pbuf, kt) do {                                                 \
  _Pragma("unroll") for (int r_ = 0; r_ < 4; ++r_)                              \
    gload_lds16(gA + (long long)(r_ * 64) * lda + (long long)(kt) * 64,         \
                &sm[(pbuf) * 24576 + r_ * 4096 + tid * 8]);                     \
} while (0)

#define STAGE_B6(pbuf, kt) do {                                                 \
  _Pragma("unroll") for (int r_ = 0; r_ < 2; ++r_)                              \
    gload_lds16(gB + (long long)(r_ * 64) * ldb + (long long)(kt) * 64,         \
                &sm[(pbuf) * 24576 + 16384 + r_ * 4096 + tid * 8]);             \
} while (0)

template<int OUT>
__global__ __launch_bounds__(512)
void gemm256x128(const unsigned short* __restrict__ A, int lda, long long strA,
                 const unsigned short* __restrict__ B, int ldb, long long strB,
                 unsigned short* __restrict__ Cg, int ldc, long long strC,
                 int K, const float* __restrict__ bias, int NBX, int NBY,
                 float* __restrict__ Rg)
{
  __shared__ unsigned short sm[49152];   // 96 KiB
  const int tid  = threadIdx.x;
  const int lane = tid & 63;
  const int wv   = tid >> 6;
  const int wrp  = wv >> 1;          // 0..3 (M quarter)
  const int wcp  = wv & 1;           // 0..1 (N half)
  const int fr   = lane & 15;

  const int nwg = gridDim.x, bid = blockIdx.x;
  const int qq = nwg >> 3, rr = nwg & 7, xc = bid & 7, ii = bid >> 3;
  const int wg = (xc < rr ? xc * (qq + 1) : rr * (qq + 1) + (xc - rr) * qq) + ii;
  const int bx = wg % NBX;
  const int tt = wg / NBX;
  const int by = tt % NBY;
  const int bz = tt / NBY;

  const long long m0 = (long long)by * 256;
  const long long n0 = (long long)bx * 128;
  const unsigned short* Ab = A + (long long)bz * strA + m0 * lda;
  const unsigned short* Bb = B + (long long)bz * strB + n0 * ldb;

  const int srow = tid >> 3;                                   // 0..63
  const int scol = ((tid & 7) * 8) ^ ((srow & 7) << 3);
  const unsigned short* gA = Ab + (long long)srow * lda + scol;
  const unsigned short* gB = Bb + (long long)srow * ldb + scol;

  const int xorc  = (fr & 7) << 3;
  const int q8    = (lane >> 4) * 8;
  const int c0    = q8 ^ xorc;
  const int c1    = (32 + q8) ^ xorc;
  const int aRow  = (wrp * 64 + fr) * 64;
  const int bRow  = 16384 + (wcp * 64 + fr) * 64;

  f32x4 acc[4][4];
#pragma unroll
  for (int i = 0; i < 4; ++i)
#pragma unroll
    for (int j = 0; j < 4; ++j) acc[i][j] = (f32x4){0.f, 0.f, 0.f, 0.f};

  bf16x8 aA[4][2], bB2[2][2];
  const int NT = K >> 6;   // >= 8 for all uses

  // prologue: A(0),B(0) -> buf0; A(1) -> buf1; vmcnt(4) retires tile 0
  STAGE_A6(0, 0);
  STAGE_B6(0, 0);
  STAGE_A6(1, 1);
  asm volatile("s_waitcnt vmcnt(4)" ::: "memory");
  __builtin_amdgcn_s_barrier();

  int p = 0;
  for (int t = 0; t < NT; ++t) {
    const int pb = p * 24576;
    const int pn = p ^ 1;
    // ---- phase 0: read A(all) + B half0; stage B(t+1) -> pn ----
    if (t + 1 < NT) STAGE_B6(pn, t + 1);
#pragma unroll
    for (int m = 0; m < 4; ++m) {
      aA[m][0] = *reinterpret_cast<const bf16x8*>(&sm[pb + aRow + m * 1024 + c0]);
      aA[m][1] = *reinterpret_cast<const bf16x8*>(&sm[pb + aRow + m * 1024 + c1]);
    }
#pragma unroll
    for (int n = 0; n < 2; ++n) {
      bB2[n][0] = *reinterpret_cast<const bf16x8*>(&sm[pb + bRow + n * 1024 + c0]);
      bB2[n][1] = *reinterpret_cast<const bf16x8*>(&sm[pb + bRow + n * 1024 + c1]);
    }
    __builtin_amdgcn_s_setprio(1);
#pragma unroll
    for (int m = 0; m < 4; ++m)
#pragma unroll
      for (int n = 0; n < 2; ++n) {
        acc[m][n] = __builtin_amdgcn_mfma_f32_16x16x32_bf16(aA[m][0], bB2[n][0], acc[m][n], 0, 0, 0);
        acc[m][n] = __builtin_amdgcn_mfma_f32_16x16x32_bf16(aA[m][1], bB2[n][1], acc[m][n], 0, 0, 0);
      }
    __builtin_amdgcn_s_setprio(0);
    __builtin_amdgcn_s_barrier();   // all waves' A-reads of buf p complete
    // ---- phase 1: read B half1; stage A(t+2) -> p (A-region free) ----
    if (t + 2 < NT) STAGE_A6(p, t + 2);
#pragma unroll
    for (int n = 0; n < 2; ++n) {
      bB2[n][0] = *reinterpret_cast<const bf16x8*>(&sm[pb + bRow + (2 + n) * 1024 + c0]);
      bB2[n][1] = *reinterpret_cast<const bf16x8*>(&sm[pb + bRow + (2 + n) * 1024 + c1]);
    }
    __builtin_amdgcn_s_setprio(1);
#pragma unroll
    for (int m = 0; m < 4; ++m)
#pragma unroll
      for (int n = 0; n < 2; ++n) {
        acc[m][2 + n] = __builtin_amdgcn_mfma_f32_16x16x32_bf16(aA[m][0], bB2[n][0], acc[m][2 + n], 0, 0, 0);
        acc[m][2 + n] = __builtin_amdgcn_mfma_f32_16x16x32_bf16(aA[m][1], bB2[n][1], acc[m][2 + n], 0, 0, 0);
      }
    __builtin_amdgcn_s_setprio(0);
    if (t + 2 < NT) asm volatile("s_waitcnt vmcnt(4)" ::: "memory");
    else            asm volatile("s_waitcnt vmcnt(0)" ::: "memory");
    __builtin_amdgcn_s_barrier();   // tile t+1 fully staged for all waves
    p = pn;
  }

  // ---- epilogue ----
  const int rq = (lane >> 4) * 4;
  if (OUT == 1) {
#pragma unroll
    for (int m = 0; m < 4; ++m)
#pragma unroll
      for (int n = 0; n < 4; ++n)
#pragma unroll
        for (int j = 0; j < 4; ++j) acc[m][n][j] = __expf(acc[m][n][j]);
  } else if (bias) {
#pragma unroll
    for (int n = 0; n < 4; ++n) {
      const float bv = bias[n0 + wcp * 64 + n * 16 + fr];
#pragma unroll
      for (int m = 0; m < 4; ++m)
#pragma unroll
        for (int j = 0; j < 4; ++j) acc[m][n][j] += bv;
    }
  }
  float* rps = (float*)sm;               // bytes [0, 2048): [2 wcp][256 rows]
  unsigned short* cs = sm + 4096;        // bytes [8192, 77824): 256 x 136
  if (OUT == 1) {
#pragma unroll
    for (int m = 0; m < 4; ++m)
#pragma unroll
      for (int j = 0; j < 4; ++j) {
        float s = acc[m][0][j] + acc[m][1][j] + acc[m][2][j] + acc[m][3][j];
        s += __shfl_xor(s, 1); s += __shfl_xor(s, 2);
        s += __shfl_xor(s, 4); s += __shfl_xor(s, 8);
        const int lrow = wrp * 64 + m * 16 + rq + j;
        if (fr == 0) rps[wcp * 256 + lrow] = s;
      }
  }
#pragma unroll
  for (int m = 0; m < 4; ++m)
#pragma unroll
    for (int j = 0; j < 4; ++j) {
      const int lrow = wrp * 64 + m * 16 + rq + j;
#pragma unroll
      for (int n = 0; n < 4; ++n)
        cs[lrow * 136 + wcp * 64 + n * 16 + fr] = f2bf(acc[m][n][j]);
    }
  __syncthreads();
  if (OUT == 1 && tid < 256) {
    const float s = rps[tid] + rps[256 + tid];
    Rg[((long long)bz * NBX + bx) * 2048 + m0 + tid] = s;
  }
  unsigned short* C = Cg + (long long)bz * strC;
#pragma unroll
  for (int it = 0; it < 8; ++it) {
    const int row = it * 32 + (tid >> 4);
    const int ch = tid & 15;
    ushort8 v = *reinterpret_cast<const ushort8*>(&cs[row * 136 + ch * 8]);
    *reinterpret_cast<ushort8*>(&C[(m0 + row) * ldc + n0 + ch * 8]) = v;
  }
}

// ---------------- invR[b][t] = 1 / sum_c R[b][c][t]  (fixed order) ----------------
__global__ __launch_bounds__(256)
void rowsum_inv_kernel(const float* __restrict__ R, float* __restrict__ invR) {
  const int i = blockIdx.x * 256 + threadIdx.x;   // 0..16383
  const int b = i >> 11, t = i & 2047;
  float s = 0.f;
#pragma unroll
  for (int c = 0; c < 16; ++c) s += R[((long long)(b * 16 + c)) * 2048 + t];
  invR[i] = 1.0f / s;
}

// ====== 128x128 PV GEMM — round-10 PASSING kernel, verbatim ======
#define STAGE_A(pbuf, kt) do {                                                  \
  _Pragma("unroll") for (int r_ = 0; r_ < 4; ++r_)                              \
    gload_lds16(gA + (long long)(r_ * 32) * lda + (long long)(kt) * 64,         \
                &sm[(pbuf) * 16384 + r_ * 2048 + tid * 8]);                     \
} while (0)

#define STAGE_B(pbuf, kt) do {                                                  \
  _Pragma("unroll") for (int r_ = 0; r_ < 4; ++r_)                              \
    gload_lds16(gB + (long long)(r_ * 32) * ldb + (long long)(kt) * 64,         \
                &sm[(pbuf) * 16384 + 8192 + r_ * 2048 + tid * 8]);              \
} while (0)

__global__ __launch_bounds__(256)
void gemm_pv(const unsigned short* __restrict__ A, int lda, long long strA,
             const unsigned short* __restrict__ B, int ldb, long long strB,
             const float* __restrict__ invR,
             float* __restrict__ C, int ldc, long long strC, int K)
{
  __shared__ unsigned short sm[32768];   // 64 KiB
  const int tid  = threadIdx.x;
  const int lane = tid & 63;
  const int wv   = tid >> 6;
  const int wrp  = wv >> 1;
  const int wcp  = wv & 1;
  const int fr   = lane & 15;

  const int nwg = gridDim.x, bid = blockIdx.x;
  const int qq = nwg >> 3, rr = nwg & 7, xc = bid & 7, ii = bid >> 3;
  const int wg = (xc < rr ? xc * (qq + 1) : rr * (qq + 1) + (xc - rr) * qq) + ii;
  const int bx = wg & 3;
  const int by = (wg >> 2) & 15;
  const int bz = wg >> 6;

  const long long m0 = (long long)by * 128;
  const long long n0 = (long long)bx * 128;
  const unsigned short* Ab = A + (long long)bz * strA + m0 * lda;
  const unsigned short* Bb = B + (long long)bz * strB + n0 * ldb;

  const int srow = tid >> 3;
  const int scol = ((tid & 7) * 8) ^ ((srow & 7) << 3);
  const unsigned short* gA = Ab + (long long)srow * lda + scol;
  const unsigned short* gB = Bb + (long long)srow * ldb + scol;

  const int xorc  = (fr & 7) << 3;
  const int q8    = (lane >> 4) * 8;
  const int c0    = q8 ^ xorc;
  const int c1    = (32 + q8) ^ xorc;
  const int aRow  = (wrp * 64 + fr) * 64;
  const int bRow  = 8192 + (wcp * 64 + fr) * 64;

  f32x4 acc[4][4];
#pragma unroll
  for (int i = 0; i < 4; ++i)
#pragma unroll
    for (int j = 0; j < 4; ++j) acc[i][j] = (f32x4){0.f, 0.f, 0.f, 0.f};

  bf16x8 aA[4][2], bB2[2][2];
  const int NT = K >> 6;

  STAGE_A(0, 0);
  STAGE_B(0, 0);
  STAGE_A(1, 1);
  asm volatile("s_waitcnt vmcnt(4)" ::: "memory");
  __builtin_amdgcn_s_barrier();

  int p = 0;
  for (int t = 0; t < NT; ++t) {
    const int pb = p * 16384;
    const int pn = p ^ 1;
    if (t + 1 < NT) STAGE_B(pn, t + 1);
#pragma unroll
    for (int m = 0; m < 4; ++m) {
      aA[m][0] = *reinterpret_cast<const bf16x8*>(&sm[pb + aRow + m * 1024 + c0]);
      aA[m][1] = *reinterpret_cast<const bf16x8*>(&sm[pb + aRow + m * 1024 + c1]);
    }
#pragma unroll
    for (int n = 0; n < 2; ++n) {
      bB2[n][0] = *reinterpret_cast<const bf16x8*>(&sm[pb + bRow + n * 1024 + c0]);
      bB2[n][1] = *reinterpret_cast<const bf16x8*>(&sm[pb + bRow + n * 1024 + c1]);
    }
    __builtin_amdgcn_s_setprio(1);
#pragma unroll
    for (int m = 0; m < 4; ++m)
#pragma unroll
      for (int n = 0; n < 2; ++n) {
        acc[m][n] = __builtin_amdgcn_mfma_f32_16x16x32_bf16(aA[m][0], bB2[n][0], acc[m][n], 0, 0, 0);
        acc[m][n] = __builtin_amdgcn_mfma_f32_16x16x32_bf16(aA[m][1], bB2[n][1], acc[m][n], 0, 0, 0);
      }
    __builtin_amdgcn_s_setprio(0);
    __builtin_amdgcn_s_barrier();
    if (t + 2 < NT) STAGE_A(p, t + 2);
#pragma unroll
    for (int n = 0; n < 2; ++n) {
      bB2[n][0] = *reinterpret_cast<const bf16x8*>(&sm[pb + bRow + (2 + n) * 1024 + c0]);
      bB2[n][1] = *reinterpret_cast<const bf16x8*>(&sm[pb + bRow + (2 + n) * 1024 + c1]);
    }
    __builtin_amdgcn_s_setprio(1);
#pragma unroll
    for (int m = 0; m < 4; ++m)
#pragma unroll
      for (int n = 0; n < 2; ++n) {
        acc[m][2 + n] = __builtin_amdgcn_mfma_f32_16x16x32_bf16(aA[m][0], bB2[n][0], acc[m][2 + n], 0, 0, 0);
        acc[m][2 + n] = __builtin_amdgcn_mfma_f32_16x16x32_bf16(aA[m][1], bB2[n][1], acc[m][2 + n], 0, 0, 0);
      }
    __builtin_amdgcn_s_setprio(0);
    if (t + 2 < NT) asm volatile("s_waitcnt vmcnt(4)" ::: "memory");
    else            asm volatile("s_waitcnt vmcnt(0)" ::: "memory");
    __builtin_amdgcn_s_barrier();
    p = pn;
  }

  const int rq = (lane >> 4) * 4;
  float* Cb = C + (long long)bz * strC;
#pragma unroll
  for (int m = 0; m < 4; ++m)
#pragma unroll
    for (int j = 0; j < 4; ++j) {
      const int lrow = wrp * 64 + m * 16 + rq + j;
      const long long row = m0 + lrow;
      const float inv = invR[bz * 2048 + row];
#pragma unroll
      for (int n = 0; n < 4; ++n)
        Cb[row * ldc + n0 + wcp * 64 + n * 16 + fr] = acc[m][n][j] * inv;
    }
}

// ---------------- launch ----------------
extern "C" void kernel_launch(void* const* d_in, const int* in_sizes, int n_in,
                              void* d_out, int out_size, void* d_ws, size_t ws_size,
                              hipStream_t stream)
{
  const float* x  = (const float*)d_in[0];
  const float* Wq = (const float*)d_in[1];
  const float* bq = (const float*)d_in[2];
  const float* Wk = (const float*)d_in[3];
  const float* bk = (const float*)d_in[4];
  float* out = (float*)d_out;

  char* w = (char*)d_ws;
  unsigned short* xbf  = (unsigned short*)w;  w += (size_t)B_ * T_ * E_ * 2;
  unsigned short* xT   = (unsigned short*)w;  w += (size_t)B_ * T_ * E_ * 2;
  unsigned short* WT   = (unsigned short*)w;  w += (size_t)2 * E_ * E_ * 2;
  float*          bqk  = (float*)w;           w += (size_t)2 * E_ * 4;
  float*          R    = (float*)w;           w += (size_t)B_ * 16 * T_ * 4;     // 2 MB
  float*          invR = (float*)w;           w += (size_t)B_ * T_ * 4;          // 64 KB
  unsigned short* qk   = (unsigned short*)w;  w += (size_t)B_ * T_ * 2 * E_ * 2;
  unsigned short* attn = (unsigned short*)w;  w += (size_t)B_ * T_ * T_ * 2;

  const float scale = 0.044194173824159216f;  // 512^-0.5

  trans_conv_kernel<<<dim3(32, 8, 8), 256, 0, stream>>>(x, xbf, xT);
  conv_w_kernel<<<2048, 256, 0, stream>>>(Wq, Wk, bq, bk, WT, bqk, scale);

  // qk[16384, 1024] = xbf @ WT^T (+bias)   grid 8x64 = 512 blocks
  gemm256x128<0><<<512, 512, 0, stream>>>(
      xbf, E_, 0, WT, E_, 0, qk, 2 * E_, 0, E_, bqk, 8, 64, nullptr);

  // P[b][2048,2048] = exp(q_b @ k_b^T) + partial rowsums   grid 16x8x8 = 1024
  gemm256x128<1><<<1024, 512, 0, stream>>>(
      qk, 2 * E_, (long long)T_ * 2 * E_,
      qk + E_, 2 * E_, (long long)T_ * 2 * E_,
      attn, T_, (long long)T_ * T_, E_, nullptr, 16, 8, R);

  rowsum_inv_kernel<<<64, 256, 0, stream>>>(R, invR);

  // out[b][2048,512] = (P_b @ x_b) * invR   grid 4x16x8 = 512
  gemm_pv<<<512, 256, 0, stream>>>(
      attn, T_, (long long)T_ * T_,
      xT, T_, (long long)E_ * T_,
      invR, out, E_, (long long)T_ * E_, T_);
}

// Round 12
// 142.463 us; speedup vs baseline: 1.0242x; 1.0041x over previous
//
#include <hip/hip_runtime.h>
#include <hip/hip_bf16.h>
#include <stdint.h>

#define B_  8
#define T_  2048
#define E_  512

typedef __attribute__((ext_vector_type(8))) __bf16 bf16x8;
typedef __attribute__((ext_vector_type(8))) unsigned short ushort8;
typedef __attribute__((ext_vector_type(4))) unsigned short ushort4v;
typedef __attribute__((ext_vector_type(4))) float f32x4;

__device__ __forceinline__ float bf2f(unsigned short u) {
  union { unsigned int u; float f; } c; c.u = ((unsigned int)u) << 16; return c.f;
}
__device__ __forceinline__ unsigned short f2bf(float f) {
  union { float f; unsigned int u; } c; c.f = f;
  unsigned int u = c.u;
  unsigned int r = (u + 0x7FFFu + ((u >> 16) & 1u)) >> 16;
  return (unsigned short)r;
}

__device__ __forceinline__ void gload_lds16(const void* g, void* l) {
  __builtin_amdgcn_global_load_lds(
      (const __attribute__((address_space(1))) uint32_t*)g,
      (__attribute__((address_space(3))) uint32_t*)l, 16, 0, 0);
}

// ---------------- fused bf16-convert + transpose ----------------
__global__ __launch_bounds__(256)
void trans_conv_kernel(const float* __restrict__ x, unsigned short* __restrict__ xbf,
                       unsigned short* __restrict__ xT) {
  __shared__ unsigned short tile[64][66];
  const int t0 = blockIdx.x * 64, e0 = blockIdx.y * 64, b = blockIdx.z;
  const int tid = threadIdx.x;
  const float* xb = x + ((size_t)b * T_ + t0) * E_ + e0;
  unsigned short* xbf_b = xbf + ((size_t)b * T_ + t0) * E_ + e0;
#pragma unroll
  for (int it = 0; it < 4; ++it) {
    int tr = (tid >> 4) + it * 16;
    int ec = (tid & 15) * 4;
    float4 f = *reinterpret_cast<const float4*>(xb + (size_t)tr * E_ + ec);
    ushort4v o;
    o[0] = f2bf(f.x); o[1] = f2bf(f.y); o[2] = f2bf(f.z); o[3] = f2bf(f.w);
    *reinterpret_cast<ushort4v*>(xbf_b + (size_t)tr * E_ + ec) = o;
    tile[ec + 0][tr] = o[0];
    tile[ec + 1][tr] = o[1];
    tile[ec + 2][tr] = o[2];
    tile[ec + 3][tr] = o[3];
  }
  __syncthreads();
  unsigned short* dst = xT + ((size_t)b * E_ + e0) * T_ + t0;
#pragma unroll
  for (int it = 0; it < 2; ++it) {
    int er = (tid >> 3) + it * 32;
    int tg = (tid & 7) * 8;
    ushort8 r;
#pragma unroll
    for (int j = 0; j < 8; ++j) r[j] = tile[er][tg + j];
    *reinterpret_cast<ushort8*>(dst + (size_t)er * T_ + tg) = r;
  }
}

// WT[n][kk] = (n<512 ? Wq[kk][n]*scale : Wk[kk][n-512]);  bqk[n] fused bias
__global__ __launch_bounds__(256)
void conv_w_kernel(const float* __restrict__ Wq, const float* __restrict__ Wk,
                   const float* __restrict__ bq, const float* __restrict__ bk,
                   unsigned short* __restrict__ WT, float* __restrict__ bqk, float scale) {
  int idx = blockIdx.x * 256 + threadIdx.x;
  int n  = idx >> 9;
  int kk = idx & 511;
  float v = (n < E_) ? Wq[kk * E_ + n] * scale : Wk[kk * E_ + (n - E_)];
  WT[idx] = f2bf(v);
  if (idx < 2 * E_) {
    float bv = (idx < E_) ? bq[idx] * scale : bk[idx - E_];
    bqk[idx] = bv;
  }
}

// ====== 128x128 GEMM, ONE barrier per K-tile: 3-buf A / 2-buf B rotation ======
// 4 waves (2M x 2N), per-wave 64x64 (acc=64 regs, spill-safe). BK=64.
// LDS 80 KiB: A bufs 3 x 8192 shorts @[0,24576), B bufs 2 x 8192 @[24576,40960).
// Window t reads A(t%3), B(t%2); stages B(t+1)->(t+1)%2 and A(t+2)->(t+2)%3.
// Every staged buffer's last READ ended >=1 barrier ago (A: 2 windows back,
// B: 1 window back) and ds_reads complete before each wave's barrier (lgkm
// dependency through MFMAs) -> single barrier suffices. Tile-end vmcnt(4)
// retires A(t+1)+B(t+1) (8 loads), keeps A(t+2)'s 4 in flight across it.
// OUT: 0 = bf16 +bias; 1 = bf16 exp + partial rowsum R; 2 = f32 * invR.
#define STG_A1(abuf_, kt) do {                                                  \
  _Pragma("unroll") for (int r_ = 0; r_ < 4; ++r_)                              \
    gload_lds16(gA + (long long)(r_ * 32) * lda + (long long)(kt) * 64,         \
                &sm[(abuf_) * 8192 + r_ * 2048 + tid * 8]);                     \
} while (0)

#define STG_B1(bbuf_, kt) do {                                                  \
  _Pragma("unroll") for (int r_ = 0; r_ < 4; ++r_)                              \
    gload_lds16(gB + (long long)(r_ * 32) * ldb + (long long)(kt) * 64,         \
                &sm[24576 + (bbuf_) * 8192 + r_ * 2048 + tid * 8]);             \
} while (0)

template<int OUT>
__global__ __launch_bounds__(256)
void gemm1b(const unsigned short* __restrict__ A, int lda, long long strA,
            const unsigned short* __restrict__ B, int ldb, long long strB,
            void* __restrict__ Cv, int ldc, long long strC,
            int K, const float* __restrict__ bias, int NBX, int NBY,
            float* __restrict__ Rg, const float* __restrict__ invR)
{
  __shared__ unsigned short sm[40960];   // 80 KiB -> 2 blocks/CU
  const int tid  = threadIdx.x;
  const int lane = tid & 63;
  const int wv   = tid >> 6;
  const int wrp  = wv >> 1;
  const int wcp  = wv & 1;
  const int fr   = lane & 15;

  const int nwg = gridDim.x, bid = blockIdx.x;
  const int qq = nwg >> 3, rr = nwg & 7, xc = bid & 7, ii = bid >> 3;
  const int wg = (xc < rr ? xc * (qq + 1) : rr * (qq + 1) + (xc - rr) * qq) + ii;
  const int bx = wg % NBX;
  const int tt = wg / NBX;
  const int by = tt % NBY;
  const int bz = tt / NBY;

  const long long m0 = (long long)by * 128;
  const long long n0 = (long long)bx * 128;
  const unsigned short* Ab = A + (long long)bz * strA + m0 * lda;
  const unsigned short* Bb = B + (long long)bz * strB + n0 * ldb;

  const int srow = tid >> 3;                                   // 0..31
  const int scol = ((tid & 7) * 8) ^ ((srow & 7) << 3);
  const unsigned short* gA = Ab + (long long)srow * lda + scol;
  const unsigned short* gB = Bb + (long long)srow * ldb + scol;

  const int xorc  = (fr & 7) << 3;
  const int q8    = (lane >> 4) * 8;
  const int c0    = q8 ^ xorc;
  const int c1    = (32 + q8) ^ xorc;
  const int aRow  = (wrp * 64 + fr) * 64;
  const int bRow  = (wcp * 64 + fr) * 64;

  f32x4 acc[4][4];
#pragma unroll
  for (int i = 0; i < 4; ++i)
#pragma unroll
    for (int j = 0; j < 4; ++j) acc[i][j] = (f32x4){0.f, 0.f, 0.f, 0.f};

  bf16x8 aA[4][2], bB4[4][2];
  const int NT = K >> 6;   // >= 8 for all uses

  // prologue: A(0)->abuf0, B(0)->bbuf0, A(1)->abuf1.
  // vmcnt(4) retires tile 0's 8 loads; A(1)'s 4 stay in flight.
  STG_A1(0, 0);
  STG_B1(0, 0);
  STG_A1(1, 1);
  asm volatile("s_waitcnt vmcnt(4)" ::: "memory");
  __builtin_amdgcn_s_barrier();

  int ab = 0;   // t % 3
  int bb = 0;   // t % 2
  for (int t = 0; t < NT; ++t) {
    // stage first so loads are in flight under this tile's compute
    if (t + 1 < NT) STG_B1(bb ^ 1, t + 1);
    if (t + 2 < NT) { int ab2 = ab + 2; if (ab2 >= 3) ab2 -= 3; STG_A1(ab2, t + 2); }
    const int pbA = ab * 8192;
    const int pbB = 24576 + bb * 8192;
#pragma unroll
    for (int m = 0; m < 4; ++m) {
      aA[m][0] = *reinterpret_cast<const bf16x8*>(&sm[pbA + aRow + m * 1024 + c0]);
      aA[m][1] = *reinterpret_cast<const bf16x8*>(&sm[pbA + aRow + m * 1024 + c1]);
    }
#pragma unroll
    for (int n = 0; n < 4; ++n) {
      bB4[n][0] = *reinterpret_cast<const bf16x8*>(&sm[pbB + bRow + n * 1024 + c0]);
      bB4[n][1] = *reinterpret_cast<const bf16x8*>(&sm[pbB + bRow + n * 1024 + c1]);
    }
    __builtin_amdgcn_s_setprio(1);
#pragma unroll
    for (int m = 0; m < 4; ++m)
#pragma unroll
      for (int n = 0; n < 4; ++n) {
        acc[m][n] = __builtin_amdgcn_mfma_f32_16x16x32_bf16(aA[m][0], bB4[n][0], acc[m][n], 0, 0, 0);
        acc[m][n] = __builtin_amdgcn_mfma_f32_16x16x32_bf16(aA[m][1], bB4[n][1], acc[m][n], 0, 0, 0);
      }
    __builtin_amdgcn_s_setprio(0);
    if (t + 2 < NT)      asm volatile("s_waitcnt vmcnt(4)" ::: "memory");
    else                 asm volatile("s_waitcnt vmcnt(0)" ::: "memory");
    __builtin_amdgcn_s_barrier();
    ab = (ab == 2) ? 0 : ab + 1;
    bb ^= 1;
  }

  // ---- epilogue (verbatim from passing r8 gemm128c) ----
  const int rq = (lane >> 4) * 4;
  if (OUT == 2) {
    float* Cb = (float*)Cv + (long long)bz * strC;
#pragma unroll
    for (int m = 0; m < 4; ++m)
#pragma unroll
      for (int j = 0; j < 4; ++j) {
        const int lrow = wrp * 64 + m * 16 + rq + j;
        const long long row = m0 + lrow;
        const float inv = invR[bz * 2048 + row];
#pragma unroll
        for (int n = 0; n < 4; ++n)
          Cb[row * ldc + n0 + wcp * 64 + n * 16 + fr] = acc[m][n][j] * inv;
      }
    return;
  }
  if (OUT == 1) {
#pragma unroll
    for (int m = 0; m < 4; ++m)
#pragma unroll
      for (int n = 0; n < 4; ++n)
#pragma unroll
        for (int j = 0; j < 4; ++j) acc[m][n][j] = __expf(acc[m][n][j]);
    float* rps = (float*)(sm + 17664);
#pragma unroll
    for (int m = 0; m < 4; ++m)
#pragma unroll
      for (int j = 0; j < 4; ++j) {
        float s = acc[m][0][j] + acc[m][1][j] + acc[m][2][j] + acc[m][3][j];
        s += __shfl_xor(s, 1); s += __shfl_xor(s, 2);
        s += __shfl_xor(s, 4); s += __shfl_xor(s, 8);
        if (fr == 0) rps[wcp * 128 + wrp * 64 + m * 16 + rq + j] = s;
      }
  } else if (bias) {
#pragma unroll
    for (int n = 0; n < 4; ++n) {
      const float bv = bias[n0 + wcp * 64 + n * 16 + fr];
#pragma unroll
      for (int m = 0; m < 4; ++m)
#pragma unroll
        for (int j = 0; j < 4; ++j) acc[m][n][j] += bv;
    }
  }
  // C-stage into LDS (136-short padded rows), coalesced ushort8 stores
#pragma unroll
  for (int m = 0; m < 4; ++m)
#pragma unroll
    for (int j = 0; j < 4; ++j) {
      const int lrow = wrp * 64 + m * 16 + rq + j;
#pragma unroll
      for (int n = 0; n < 4; ++n)
        sm[lrow * 136 + wcp * 64 + n * 16 + fr] = f2bf(acc[m][n][j]);
    }
  __syncthreads();
  if (OUT == 1) {
    float* rps = (float*)(sm + 17664);
    if (tid < 128) {
      const float s = rps[tid] + rps[128 + tid];
      Rg[((long long)bz * NBX + bx) * 2048 + m0 + tid] = s;
    }
  }
  unsigned short* C = (unsigned short*)Cv + (long long)bz * strC;
#pragma unroll
  for (int it = 0; it < 8; ++it) {
    const int row = it * 16 + (tid >> 4);
    const int chunk = tid & 15;
    ushort8 v = *reinterpret_cast<const ushort8*>(&sm[row * 136 + chunk * 8]);
    *reinterpret_cast<ushort8*>(&C[(m0 + row) * ldc + n0 + chunk * 8]) = v;
  }
}

// ---------------- invR[b][t] = 1 / sum_c R[b][c][t]  (fixed order) ----------------
__global__ __launch_bounds__(256)
void rowsum_inv_kernel(const float* __restrict__ R, float* __restrict__ invR) {
  const int i = blockIdx.x * 256 + threadIdx.x;   // 0..16383
  const int b = i >> 11, t = i & 2047;
  float s = 0.f;
#pragma unroll
  for (int c = 0; c < 16; ++c) s += R[((long long)(b * 16 + c)) * 2048 + t];
  invR[i] = 1.0f / s;
}

// ---------------- launch ----------------
extern "C" void kernel_launch(void* const* d_in, const int* in_sizes, int n_in,
                              void* d_out, int out_size, void* d_ws, size_t ws_size,
                              hipStream_t stream)
{
  const float* x  = (const float*)d_in[0];
  const float* Wq = (const float*)d_in[1];
  const float* bq = (const float*)d_in[2];
  const float* Wk = (const float*)d_in[3];
  const float* bk = (const float*)d_in[4];
  float* out = (float*)d_out;

  char* w = (char*)d_ws;
  unsigned short* xbf  = (unsigned short*)w;  w += (size_t)B_ * T_ * E_ * 2;
  unsigned short* xT   = (unsigned short*)w;  w += (size_t)B_ * T_ * E_ * 2;
  unsigned short* WT   = (unsigned short*)w;  w += (size_t)2 * E_ * E_ * 2;
  float*          bqk  = (float*)w;           w += (size_t)2 * E_ * 4;
  float*          R    = (float*)w;           w += (size_t)B_ * 16 * T_ * 4;     // 2 MB
  float*          invR = (float*)w;           w += (size_t)B_ * T_ * 4;          // 64 KB
  unsigned short* qk   = (unsigned short*)w;  w += (size_t)B_ * T_ * 2 * E_ * 2;
  unsigned short* attn = (unsigned short*)w;  w += (size_t)B_ * T_ * T_ * 2;

  const float scale = 0.044194173824159216f;  // 512^-0.5

  trans_conv_kernel<<<dim3(32, 8, 8), 256, 0, stream>>>(x, xbf, xT);
  conv_w_kernel<<<2048, 256, 0, stream>>>(Wq, Wk, bq, bk, WT, bqk, scale);

  // qk[16384, 1024] = xbf @ WT^T (+bias)   grid 8x128 = 1024 blocks
  gemm1b<0><<<1024, 256, 0, stream>>>(
      xbf, E_, 0, WT, E_, 0, qk, 2 * E_, 0, E_, bqk, 8, 128, nullptr, nullptr);

  // P[b][2048,2048] = exp(q_b @ k_b^T) + partial rowsums   grid 16x16x8 = 2048
  gemm1b<1><<<2048, 256, 0, stream>>>(
      qk, 2 * E_, (long long)T_ * 2 * E_,
      qk + E_, 2 * E_, (long long)T_ * 2 * E_,
      attn, T_, (long long)T_ * T_, E_, nullptr, 16, 16, R, nullptr);

  rowsum_inv_kernel<<<64, 256, 0, stream>>>(R, invR);

  // out[b][2048,512] = (P_b @ x_b) * invR   grid 4x16x8 = 512
  gemm1b<2><<<512, 256, 0, stream>>>(
      attn, T_, (long long)T_ * T_,
      xT, T_, (long long)E_ * T_,
      out, E_, (long long)T_ * E_, T_, nullptr, 4, 16, nullptr, invR);
}